// Round 15
// baseline (414.200 us; speedup 1.0000x reference)
//
#include <hip/hip_runtime.h>

// out[b,s,j] = sum_k x[b,s,k] * w_concat[inv_perm[j], k] + bias[j]
// INT8 path: weights exact in i8; x per-token quantized (sx = absmax/127).
// Round 14: WAVE-GROUP STAGGER. 8 waves = 2 groups (G0 rows[0,128), G1
// rows[128,256)); schedules offset by ONE barrier interval so every interval
// has one group doing a 16-MFMA cluster while the other group ds_reads.
// Converts the measured pipe-SUM (MFMA 2613 + LDS 2304 cyc/K-tile) toward
// per-interval max. A group-private, B shared. Liveness: every gl_lds
// overwrite sits behind a barrier following all readers' lgkm drains;
// stager's vmcnt(0) (G0 @iv7-end, G1 @iv0-end) publishes writes before the
// barrier preceding the readers.

#define M_TOK 16384
#define N_O   4096
#define K_IN  4096
#define N8F   2048
#define NT    (K_IN / 128)   // 32 K-tiles of BK=128 i8 (128 B/row)

typedef __attribute__((ext_vector_type(4))) int i32x4;

__device__ __forceinline__ void gl_lds16(const void* g, void* l) {
  __builtin_amdgcn_global_load_lds(
      (const __attribute__((address_space(1))) unsigned int*)g,
      (__attribute__((address_space(3))) unsigned int*)l, 16, 0, 0);
}

__device__ __forceinline__ int clampq(float f) {
  int q = (int)rintf(f);
  return q > 127 ? 127 : (q < -127 ? -127 : q);
}

// ---- fused prep: blocks [0,N_O) pack weights to i8; blocks [N_O, N_O+M_TOK)
// ---- quantize one token each (absmax -> sx, xq). Row-major i8, 4096 B rows.
__global__ void prep_kernel(const float* __restrict__ x,
                            const int4* __restrict__ q8, const float* __restrict__ s8,
                            const int4* __restrict__ q4, const float* __restrict__ s4,
                            const int* __restrict__ inv,
                            char* __restrict__ Wq, float* __restrict__ scale,
                            float* __restrict__ sx, char* __restrict__ xq) {
  __shared__ float red[4];
  const int t = threadIdx.x;
  if (blockIdx.x < N_O) {
    const int j = blockIdx.x;
    const int c = inv[j];
    const int4* src; float s;
    if (c < N8F) { src = q8 + (size_t)c * (K_IN / 4);         s = s8[c]; }
    else         { src = q4 + (size_t)(c - N8F) * (K_IN / 4); s = s4[c - N8F]; }
    if (t == 0) scale[j] = s;
    unsigned dw[4];
#pragma unroll
    for (int i = 0; i < 4; ++i) {
      int4 v = src[t * 4 + i];
      dw[i] = (v.x & 255) | ((v.y & 255) << 8) | ((v.z & 255) << 16)
            | ((unsigned)(v.w & 255) << 24);
    }
    *(uint4*)(Wq + (size_t)j * K_IN + t * 16) = make_uint4(dw[0], dw[1], dw[2], dw[3]);
  } else {
    const int T = blockIdx.x - N_O;
    const float4* xr = (const float4*)(x + (size_t)T * K_IN);
    float4 v[4];
    float m = 0.f;
#pragma unroll
    for (int i = 0; i < 4; ++i) {
      v[i] = xr[t * 4 + i];
      m = fmaxf(m, fmaxf(fmaxf(fabsf(v[i].x), fabsf(v[i].y)),
                         fmaxf(fabsf(v[i].z), fabsf(v[i].w))));
    }
#pragma unroll
    for (int o = 32; o; o >>= 1) m = fmaxf(m, __shfl_xor(m, o));
    if ((t & 63) == 0) red[t >> 6] = m;
    __syncthreads();
    m = fmaxf(fmaxf(red[0], red[1]), fmaxf(red[2], red[3]));
    const float rq = m > 0.f ? 127.f / m : 0.f;
    if (t == 0) sx[T] = m * (1.f / 127.f);
    unsigned dw[4];
#pragma unroll
    for (int i = 0; i < 4; ++i) {
      int a0 = clampq(v[i].x * rq), a1 = clampq(v[i].y * rq);
      int a2 = clampq(v[i].z * rq), a3 = clampq(v[i].w * rq);
      dw[i] = (a0 & 255) | ((a1 & 255) << 8) | ((a2 & 255) << 16)
            | ((unsigned)(a3 & 255) << 24);
    }
    *(uint4*)(xq + (size_t)T * K_IN + t * 16) = make_uint4(dw[0], dw[1], dw[2], dw[3]);
  }
}

// ================= 256x256 i8 GEMM, BK=128, staggered wave-groups =================
// LDS map (bytes): A0 [0,32768): buf*16384 ; A1 [32768,65536): +buf*16384
//                  B  [65536,131072): buf*32768 + row*128 (rows=cols 0..255)
// swizzle: phys_colbyte = logical ^ ((row&7)<<4), via pre-swizzled gl_lds source.

#define BAR  __builtin_amdgcn_s_barrier()
#define SB0  __builtin_amdgcn_sched_barrier(0)
#define LG0  asm volatile("s_waitcnt lgkmcnt(0)" ::: "memory")
#define VM0  asm volatile("s_waitcnt vmcnt(0)" ::: "memory")

#define RD_B(rB)                                                     \
  _Pragma("unroll") for (int n_ = 0; n_ < 4; ++n_) {                 \
    bfr[n_][0] = *(const i32x4*)((rB) + n_ * 2048 + cb0);            \
    bfr[n_][1] = *(const i32x4*)((rB) + n_ * 2048 + (cb0 ^ 64));     \
  }

#define RD_A(rA, MB, DST)                                            \
  _Pragma("unroll") for (int m_ = 0; m_ < 2; ++m_) {                 \
    DST[m_][0] = *(const i32x4*)((rA) + ((MB) + m_) * 2048 + cb0);   \
    DST[m_][1] = *(const i32x4*)((rA) + ((MB) + m_) * 2048 + (cb0 ^ 64)); \
  }

#define MFCL(MB, AF)                                                 \
  __builtin_amdgcn_s_setprio(1);                                     \
  _Pragma("unroll") for (int m_ = 0; m_ < 2; ++m_)                   \
  _Pragma("unroll") for (int n_ = 0; n_ < 4; ++n_)                   \
  _Pragma("unroll") for (int kk_ = 0; kk_ < 2; ++kk_)                \
    acc[(MB) + m_][n_] = __builtin_amdgcn_mfma_i32_16x16x64_i8(      \
        AF[m_][kk_], bfr[n_][kk_], acc[(MB) + m_][n_], 0, 0, 0);     \
  __builtin_amdgcn_s_setprio(0);

// One K-tile, CUR = literal parity. G0: reads@iv0/2/4, MFMA@iv1/3/5/7, stages
// B-h0@iv3, A0(kt+1)@iv6, vmcnt(0)@iv7-end. G1 (lag 1): MFMA P4(kt-1)@iv0,
// reads@iv1/3/5, MFMA@iv2/4/6, stages B-h1@iv4, A1(kt+1)@iv7, vmcnt(0)@iv0-end.
#define STAG_TILE(CUR, KT)                                           \
  {                                                                  \
    const char* rA = rAb + (CUR) * 16384;                            \
    const char* rB = rBb + (CUR) * 32768;                            \
    /* iv0 */                                                        \
    if (isG0) { RD_B(rB); RD_A(rA, 0, afr); }                        \
    else {                                                           \
      if ((KT) > 0) { LG0; SB0; MFCL(6, afr2); }                     \
      VM0; SB0;                                                      \
    }                                                                \
    BAR;                                                             \
    /* iv1 */                                                        \
    if (isG0) { LG0; SB0; MFCL(0, afr); }                            \
    else { RD_B(rB); RD_A(rA, 0, afr); }                             \
    BAR;                                                             \
    /* iv2 */                                                        \
    if (isG0) { RD_A(rA, 2, afr); }                                  \
    else { LG0; SB0; MFCL(0, afr); }                                 \
    BAR;                                                             \
    /* iv3 */                                                        \
    if (isG0) { if ((KT) + 2 < NT) stB((CUR), (KT) + 2);             \
                LG0; SB0; MFCL(2, afr); }                            \
    else { RD_A(rA, 2, afr); }                                       \
    BAR;                                                             \
    /* iv4 */                                                        \
    if (isG0) { RD_A(rA, 4, afr); RD_A(rA, 6, afr2); }               \
    else { if ((KT) + 2 < NT) stB((CUR), (KT) + 2);                  \
           LG0; SB0; MFCL(2, afr); }                                 \
    BAR;                                                             \
    /* iv5 */                                                        \
    if (isG0) { LG0; SB0; MFCL(4, afr); }                            \
    else { RD_A(rA, 4, afr); RD_A(rA, 6, afr2); }                    \
    BAR;                                                             \
    /* iv6 */                                                        \
    if (isG0) { if ((KT) + 1 < NT) stA((CUR) ^ 1, (KT) + 1); }       \
    else { LG0; SB0; MFCL(4, afr); }                                 \
    BAR;                                                             \
    /* iv7 */                                                        \
    if (isG0) { MFCL(6, afr2); VM0; SB0; }                           \
    else { if ((KT) + 1 < NT) stA((CUR) ^ 1, (KT) + 1); }            \
    BAR;                                                             \
  }

__global__ __launch_bounds__(512, 2)
void gemm_i8(const char* __restrict__ xq, const char* __restrict__ Wq,
             const float* __restrict__ sx, const float* __restrict__ scale,
             const float* __restrict__ bias, float* __restrict__ out) {
  __shared__ __align__(16) char sm[131072];
  const int t = threadIdx.x;
  const int w = t >> 6, l = t & 63;
  const int grp = w >> 2;                     // wave group (M-half)
  const int wq = w & 3;                       // N-column / staging slice in group
  const bool isG0 = (grp == 0);
  const int bm = blockIdx.x >> 4, bn = blockIdx.x & 15;
  const int row0 = bm * 256, col0 = bn * 256;

  // --- staging: per-lane pre-swizzled global source (rule #21) ---
  const int srow = l >> 3;
  const int schunk = ((l & 7) ^ srow) * 16;
  const char* aGs = xq + (size_t)(row0 + grp * 128 + wq * 32 + srow) * K_IN + schunk;
  const char* bGs = Wq + (size_t)(col0 + grp * 128 + wq * 32 + srow) * K_IN + schunk;
  char* aDb = sm + grp * 32768 + wq * 4096;           // + buf*16384 + i*1024
  char* bDb = sm + 65536 + grp * 16384 + wq * 4096;   // + buf*32768 + i*1024

  auto stA = [&](int buf, int kt) {                    // group's own A 128 rows
#pragma unroll
    for (int i = 0; i < 4; ++i)
      gl_lds16(aGs + (size_t)(8 * i) * K_IN + ((size_t)kt << 7),
               aDb + buf * 16384 + i * 1024);
  };
  auto stB = [&](int buf, int kt) {                    // group's B half (128 cols)
#pragma unroll
    for (int i = 0; i < 4; ++i)
      gl_lds16(bGs + (size_t)(8 * i) * K_IN + ((size_t)kt << 7),
               bDb + buf * 32768 + i * 1024);
  };

  // --- fragment-read bases (swizzled) ---
  const int lrow128 = (l & 15) * 128;
  const int cb0 = (((l >> 4) << 4) ^ ((l & 7) << 4));
  const char* rAb = sm + grp * 32768 + lrow128;        // + CUR*16384 + m*2048
  const char* rBb = sm + 65536 + wq * 8192 + lrow128;  // + CUR*32768 + n*2048

  i32x4 acc[8][4];
#pragma unroll
  for (int m = 0; m < 8; ++m)
#pragma unroll
    for (int n = 0; n < 4; ++n) acc[m][n] = (i32x4){0, 0, 0, 0};

  // --- prologue: A(0), B(0) -> buf0 ; B(1) -> buf1 ; publish ---
  stA(0, 0); stB(0, 0); stB(1, 1);
  VM0;
  BAR;

  i32x4 bfr[4][2], afr[2][2], afr2[2][2];

  for (int kt = 0; kt < NT; kt += 2) {
    STAG_TILE(0, kt);
    STAG_TILE(1, kt + 1);
  }
  // tail: G1 finishes P4 of tile NT-1 (reads drained before its iv6 MFMA)
  if (!isG0) { LG0; SB0; MFCL(6, afr2); }

  // ---- epilogue: C/D col=lane&15, row=(lane>>4)*4+i ; out = acc*sx[r]*sc + bias
  const int orow0 = row0 + grp * 128 + ((l >> 4) << 2);
  const int ocol0 = col0 + wq * 64 + (l & 15);
#pragma unroll
  for (int n = 0; n < 4; ++n) {
    const int col = ocol0 + n * 16;
    const float sc = scale[col];
    const float bi = bias[col];
#pragma unroll
    for (int m = 0; m < 8; ++m) {
      const int r = orow0 + m * 16;
      const float4 sxv = *(const float4*)(sx + r);
      out[(size_t)(r + 0) * N_O + col] = (float)acc[m][n][0] * (sxv.x * sc) + bi;
      out[(size_t)(r + 1) * N_O + col] = (float)acc[m][n][1] * (sxv.y * sc) + bi;
      out[(size_t)(r + 2) * N_O + col] = (float)acc[m][n][2] * (sxv.z * sc) + bi;
      out[(size_t)(r + 3) * N_O + col] = (float)acc[m][n][3] * (sxv.w * sc) + bi;
    }
  }
}

extern "C" void kernel_launch(void* const* d_in, const int* in_sizes, int n_in,
                              void* d_out, int out_size, void* d_ws, size_t ws_size,
                              hipStream_t stream) {
  const float* x    = (const float*)d_in[0];
  const int*   q8   = (const int*)d_in[1];
  const float* s8   = (const float*)d_in[2];
  const int*   q4   = (const int*)d_in[3];
  const float* s4   = (const float*)d_in[4];
  const int*   inv  = (const int*)d_in[5];
  const float* bias = (const float*)d_in[6];
  float* out = (float*)d_out;

  // ws layout: Wq (16 MiB) | scale (16 KiB) | sx (64 KiB) | xq (64 MiB)
  char* ws = (char*)d_ws;
  char*  Wq    = ws;
  float* scale = (float*)(ws + (size_t)N_O * K_IN);
  float* sx    = (float*)(ws + (size_t)N_O * K_IN + 65536);
  char*  xq    = ws + (size_t)N_O * K_IN + 65536 + 65536;

  prep_kernel<<<N_O + M_TOK, 256, 0, stream>>>(x, (const int4*)q8, s8,
                                               (const int4*)q4, s4, inv,
                                               Wq, scale, sx, xq);
  gemm_i8<<<(M_TOK / 256) * (N_O / 256), 512, 0, stream>>>(xq, Wq, sx, scale,
                                                           bias, out);
}